// Round 1
// baseline (817.457 us; speedup 1.0000x reference)
//
#include <hip/hip_runtime.h>

typedef unsigned short u16;
typedef __attribute__((ext_vector_type(8))) short bf16x8;
typedef __attribute__((ext_vector_type(4))) float f32x4;
typedef __attribute__((ext_vector_type(8))) unsigned short u16x8;
typedef __attribute__((ext_vector_type(4))) unsigned short u16x4;

__device__ __forceinline__ u16 f2bf(float f){
  unsigned int u = __builtin_bit_cast(unsigned int, f);
  u += 0x7FFFu + ((u >> 16) & 1u);
  return (u16)(u >> 16);
}

__device__ __forceinline__ void load16(const u16* g, u16* s){
  __builtin_amdgcn_global_load_lds((const __attribute__((address_space(1))) unsigned int*)g,
                                   (__attribute__((address_space(3))) unsigned int*)s,
                                   16, 0, 0);
}

// M[b] = (1+1e-6) I + 0.5 (A - A^T), per 512x512 block
__global__ __launch_bounds__(256) void build_M(const float* __restrict__ R, float* __restrict__ M){
  int idx = blockIdx.x * 256 + threadIdx.x;
  int b = idx >> 18;
  int i = (idx >> 9) & 511;
  int j = idx & 511;
  float a  = R[idx];
  float at = R[(b << 18) + (j << 9) + i];
  float v = 0.5f * (a - at);
  if (i == j) v += 1.000001f;
  M[idx] = v;
}

// X0 = 2I - M
__global__ __launch_bounds__(256) void init_X(const float* __restrict__ M, float* __restrict__ X){
  int idx = blockIdx.x * 256 + threadIdx.x;
  int i = (idx >> 9) & 511;
  int j = idx & 511;
  X[idx] = ((i == j) ? 2.0f : 0.0f) - M[idx];
}

// batched (z=8) 512x512x512 f32 gemm. mode 0: C = 2I - A@B ; mode 1: C = A@B
__global__ __launch_bounds__(256) void gemm512_f32(const float* __restrict__ A, const float* __restrict__ B,
                                                   float* __restrict__ C, int mode){
  const int b = blockIdx.z;
  const float* Ab = A + ((size_t)b << 18);
  const float* Bb = B + ((size_t)b << 18);
  float* Cb = C + ((size_t)b << 18);
  const int i0 = blockIdx.y << 6, j0 = blockIdx.x << 6;
  __shared__ __align__(16) float At[16][68];   // transposed A tile: At[k][i]
  __shared__ __align__(16) float Bt[16][68];   // B tile: Bt[k][j]
  const int t = threadIdx.x;
  const int tx = t & 15, ty = t >> 4;
  float acc[4][4] = {};
  for (int k0 = 0; k0 < 512; k0 += 16){
    {
      int r = t >> 2, c = (t & 3) << 2;
      float4 v = *(const float4*)&Ab[(i0 + r) * 512 + k0 + c];
      At[c+0][r] = v.x; At[c+1][r] = v.y; At[c+2][r] = v.z; At[c+3][r] = v.w;
    }
    {
      int r = t >> 4, c = (t & 15) << 2;
      *(float4*)&Bt[r][c] = *(const float4*)&Bb[(k0 + r) * 512 + j0 + c];
    }
    __syncthreads();
#pragma unroll
    for (int k = 0; k < 16; ++k){
      float4 a4 = *(const float4*)&At[k][ty << 2];
      float4 b4 = *(const float4*)&Bt[k][tx << 2];
      float av[4] = {a4.x, a4.y, a4.z, a4.w};
      float bv[4] = {b4.x, b4.y, b4.z, b4.w};
#pragma unroll
      for (int ii = 0; ii < 4; ++ii)
#pragma unroll
        for (int jj = 0; jj < 4; ++jj)
          acc[ii][jj] = fmaf(av[ii], bv[jj], acc[ii][jj]);
    }
    __syncthreads();
  }
#pragma unroll
  for (int ii = 0; ii < 4; ++ii){
    int gi = i0 + (ty << 2) + ii;
    float o[4];
#pragma unroll
    for (int jj = 0; jj < 4; ++jj){
      float v = acc[ii][jj];
      if (mode == 0){
        int gj = j0 + (tx << 2) + jj;
        v = ((gi == gj) ? 2.0f : 0.0f) - v;
      }
      o[jj] = v;
    }
    *(float4*)&Cb[gi * 512 + j0 + (tx << 2)] = make_float4(o[0], o[1], o[2], o[3]);
  }
}

// vectorized f32 -> bf16 (8 elems / thread, exact multiple)
__global__ __launch_bounds__(256) void conv_bf16(const float* __restrict__ src, u16* __restrict__ dst){
  size_t i = (size_t)blockIdx.x * 256 + threadIdx.x;
  const float4* s = (const float4*)src + i * 2;
  float4 v0 = s[0], v1 = s[1];
  u16x8 o = { f2bf(v0.x), f2bf(v0.y), f2bf(v0.z), f2bf(v0.w),
              f2bf(v1.x), f2bf(v1.y), f2bf(v1.z), f2bf(v1.w) };
  *(u16x8*)(dst + i * 8) = o;
}

// Wt[b][i][j] = W[b*512 + j][i]  (bf16), i in [0,4096), j in [0,512)
__global__ __launch_bounds__(256) void transpose_w(const float* __restrict__ W, u16* __restrict__ Wt){
  const int b = blockIdx.z;
  const int i0 = blockIdx.x << 5;
  const int j0 = blockIdx.y << 5;
  __shared__ float tile[32][33];
  const int t = threadIdx.x;
  const int r = t >> 3, c = (t & 7) << 2;
  float4 v = *(const float4*)&W[(size_t)((b << 9) + j0 + r) * 4096 + i0 + c];
  tile[r][c+0] = v.x; tile[r][c+1] = v.y; tile[r][c+2] = v.z; tile[r][c+3] = v.w;
  __syncthreads();
  u16x4 o = { f2bf(tile[c+0][r]), f2bf(tile[c+1][r]), f2bf(tile[c+2][r]), f2bf(tile[c+3][r]) };
  *(u16x4*)&Wt[((size_t)b << 21) + (size_t)(i0 + r) * 512 + j0 + c] = o;
}

// bt-form bf16 MFMA gemm (m97 structure): C[m,n] = sum_k A[m,k]*B[n,k]
// 128x128 tile, BK=32, 4 waves (2x2), 4x4 16x16x32 frags per wave.
// EPI 0: f32 out[m*N+n] = acc + aux[n]                  (aux = bias)
// EPI 1: bf16 filt = 2.000001*acc - aux[(bz*512+m)*4096+n]  (aux = weight)
template<int EPI>
__global__ __launch_bounds__(256) void gemm_bt(const u16* __restrict__ A, const u16* __restrict__ B,
                                               void* __restrict__ Cout, const float* __restrict__ aux,
                                               int M, int N, int K){
  const int bz = blockIdx.z;
  const u16* Ab = A + (size_t)bz * M * K;
  const u16* Bb = B + (size_t)bz * N * K;
  const int m0 = blockIdx.y << 7, n0 = blockIdx.x << 7;
  __shared__ __align__(16) u16 As[4096];
  __shared__ __align__(16) u16 Bs[4096];
  const int t = threadIdx.x;
  const int w = t >> 6, l = t & 63;
  const int wr = w >> 1, wc = w & 1;
  const int kofs = (l & 3) << 3;   // k offset within BK for staging
  const int rA = l >> 2;           // row-within-16 for staging
  const int aRd = ((wr << 6) + (l & 15)) * 32 + ((l >> 4) << 3);
  const int bRd = ((wc << 6) + (l & 15)) * 32 + ((l >> 4) << 3);
  f32x4 acc[4][4] = {};
  for (int k0 = 0; k0 < K; k0 += 32){
#pragma unroll
    for (int j = 0; j < 2; ++j){
      int rowBase = ((w << 1) + j) << 4;
      load16(&Ab[(size_t)(m0 + rowBase + rA) * K + k0 + kofs], &As[((w << 1) + j) << 9]);
      load16(&Bb[(size_t)(n0 + rowBase + rA) * K + k0 + kofs], &Bs[((w << 1) + j) << 9]);
    }
    __syncthreads();
    bf16x8 aF[4], bF[4];
#pragma unroll
    for (int mf = 0; mf < 4; ++mf) aF[mf] = *(const bf16x8*)&As[aRd + (mf << 9)];
#pragma unroll
    for (int nf = 0; nf < 4; ++nf) bF[nf] = *(const bf16x8*)&Bs[bRd + (nf << 9)];
#pragma unroll
    for (int mf = 0; mf < 4; ++mf)
#pragma unroll
      for (int nf = 0; nf < 4; ++nf)
        acc[mf][nf] = __builtin_amdgcn_mfma_f32_16x16x32_bf16(aF[mf], bF[nf], acc[mf][nf], 0, 0, 0);
    __syncthreads();
  }
#pragma unroll
  for (int mf = 0; mf < 4; ++mf){
#pragma unroll
    for (int nf = 0; nf < 4; ++nf){
      const int col = n0 + (wc << 6) + (nf << 4) + (l & 15);
#pragma unroll
      for (int q = 0; q < 4; ++q){
        const int row = m0 + (wr << 6) + (mf << 4) + ((l >> 4) << 2) + q;
        float v = acc[mf][nf][q];
        if (EPI == 0){
          ((float*)Cout)[(size_t)row * N + col] = v + aux[col];
        } else {
          size_t gi = (size_t)((bz << 9) + row) * 4096 + col;
          ((u16*)Cout)[gi] = f2bf(2.000001f * v - aux[gi]);
        }
      }
    }
  }
}

extern "C" void kernel_launch(void* const* d_in, const int* in_sizes, int n_in,
                              void* d_out, int out_size, void* d_ws, size_t ws_size,
                              hipStream_t stream){
  const float* W    = (const float*)d_in[0];
  const float* bias = (const float*)d_in[1];
  const float* x    = (const float*)d_in[2];
  const float* R    = (const float*)d_in[3];
  (void)in_sizes; (void)n_in; (void)out_size; (void)ws_size;

  char* ws = (char*)d_ws;
  const size_t MiB = (size_t)1 << 20;
  float* Mb   = (float*)(ws + 0 * MiB);    // 8 MiB
  float* Xa   = (float*)(ws + 8 * MiB);    // 8 MiB
  float* Xb   = (float*)(ws + 16 * MiB);   // 8 MiB
  float* Yb   = (float*)(ws + 24 * MiB);   // 8 MiB
  u16*   Xbf  = (u16*)(ws + 32 * MiB);     // 4 MiB
  u16*   Wt   = (u16*)(ws + 36 * MiB);     // 32 MiB (ends at 68)
  u16*   filt = (u16*)(ws + 68 * MiB);     // 32 MiB (ends at 100)
  u16*   xbf  = (u16*)(ws + 0 * MiB);      // 64 MiB, aliases NS/Wt region (used after they are dead)

  // Phase 1: M = cI + S
  build_M<<<8192, 256, 0, stream>>>(R, Mb);
  // Phase 2: Newton-Schulz, X -> M^{-1}
  init_X<<<8192, 256, 0, stream>>>(Mb, Xa);
  float* cur = Xa; float* nxt = Xb;
  for (int it = 0; it < 5; ++it){
    gemm512_f32<<<dim3(8, 8, 8), 256, 0, stream>>>(Mb, cur, Yb, 0);   // Y = 2I - M@X
    gemm512_f32<<<dim3(8, 8, 8), 256, 0, stream>>>(cur, Yb, nxt, 1);  // X' = X@Y
    float* tmp = cur; cur = nxt; nxt = tmp;
  }
  // Phase 3: bf16 operands for filt GEMM
  conv_bf16<<<1024, 256, 0, stream>>>(cur, Xbf);                      // 2M elems
  transpose_w<<<dim3(128, 16, 8), 256, 0, stream>>>(W, Wt);
  // Phase 4: filt = (c+1) * Minv @ W - W   (bf16 out)
  gemm_bt<1><<<dim3(32, 4, 8), 256, 0, stream>>>(Xbf, Wt, (void*)filt, W, 512, 4096, 512);
  // Phase 5: x -> bf16 (aliases dead NS/Wt region)
  conv_bf16<<<16384, 256, 0, stream>>>(x, xbf);                       // 32M elems
  // Phase 6: out = x @ filt^T + bias
  gemm_bt<0><<<dim3(32, 64, 1), 256, 0, stream>>>(xbf, filt, d_out, bias, 8192, 4096, 4096);
}

// Round 4
// 539.126 us; speedup vs baseline: 1.5163x; 1.5163x over previous
//
#include <hip/hip_runtime.h>

typedef unsigned short u16;
typedef __attribute__((ext_vector_type(8))) short bf16x8;
typedef __attribute__((ext_vector_type(4))) float f32x4;
typedef __attribute__((ext_vector_type(8))) unsigned short u16x8;
typedef __attribute__((ext_vector_type(4))) unsigned short u16x4;

__device__ __forceinline__ u16 f2bf(float f){
  unsigned int u = __builtin_bit_cast(unsigned int, f);
  u += 0x7FFFu + ((u >> 16) & 1u);
  return (u16)(u >> 16);
}
__device__ __forceinline__ float bf2f(u16 h){
  unsigned int u = ((unsigned int)h) << 16;
  return __builtin_bit_cast(float, u);
}

__device__ __forceinline__ void load16(const u16* g, u16* s){
  __builtin_amdgcn_global_load_lds((const __attribute__((address_space(1))) unsigned int*)g,
                                   (__attribute__((address_space(3))) unsigned int*)s,
                                   16, 0, 0);
}

// From R: S = 0.5(A-A^T); M = (1+1e-6)I + S; Mh = bf16(M); Ml = bf16(M - Mh);
// X0 = bf16((1-1e-6)I - S); X0t = bf16((1-1e-6)I + S)
__global__ __launch_bounds__(256) void build_ns(const float* __restrict__ R, u16* __restrict__ Mh,
                                                u16* __restrict__ Ml, u16* __restrict__ X0,
                                                u16* __restrict__ X0t){
  int idx = blockIdx.x * 256 + threadIdx.x;
  int b = idx >> 18;
  int i = (idx >> 9) & 511;
  int j = idx & 511;
  float a  = R[idx];
  float at = R[(b << 18) + (j << 9) + i];
  float s = 0.5f * (a - at);
  float m = s + (i == j ? 1.000001f : 0.0f);
  u16 mh = f2bf(m);
  Mh[idx] = mh;
  Ml[idx] = f2bf(m - bf2f(mh));
  float d = (i == j ? 0.999999f : 0.0f);
  X0[idx]  = f2bf(d - s);
  X0t[idx] = f2bf(d + s);
}

// vectorized f32 -> bf16 (8 elems / thread, exact multiple)
__global__ __launch_bounds__(256) void conv_bf16(const float* __restrict__ src, u16* __restrict__ dst){
  size_t i = (size_t)blockIdx.x * 256 + threadIdx.x;
  const float4* s = (const float4*)src + i * 2;
  float4 v0 = s[0], v1 = s[1];
  u16x8 o = { f2bf(v0.x), f2bf(v0.y), f2bf(v0.z), f2bf(v0.w),
              f2bf(v1.x), f2bf(v1.y), f2bf(v1.z), f2bf(v1.w) };
  *(u16x8*)(dst + i * 8) = o;
}

// Wt[b][i][j] = W[b*512 + j][i]  (bf16), i in [0,4096), j in [0,512)
__global__ __launch_bounds__(256) void transpose_w(const float* __restrict__ W, u16* __restrict__ Wt){
  const int b = blockIdx.z;
  const int i0 = blockIdx.x << 5;
  const int j0 = blockIdx.y << 5;
  __shared__ float tile[32][33];
  const int t = threadIdx.x;
  const int r = t >> 3, c = (t & 7) << 2;
  float4 v = *(const float4*)&W[(size_t)((b << 9) + j0 + r) * 4096 + i0 + c];
  tile[r][c+0] = v.x; tile[r][c+1] = v.y; tile[r][c+2] = v.z; tile[r][c+3] = v.w;
  __syncthreads();
  u16x4 o = { f2bf(tile[c+0][r]), f2bf(tile[c+1][r]), f2bf(tile[c+2][r]), f2bf(tile[c+3][r]) };
  *(u16x4*)&Wt[((size_t)b << 21) + (size_t)(i0 + r) * 512 + j0 + c] = o;
}

// 128x128-tile bt-form bf16 MFMA gemm (m97 structure), used for the small NS gemms.
// C[m,n] = sum_k A[m,k]*B[n,k], batched over blockIdx.z.
// EPI 2: bf16 C = acc
// EPI 3: bf16 C = 2*diag - acc
// EPI 4: f32  C = diag - acc
// EPI 5: f32  C = C - acc          (read-modify-write)
// EPI 6: bf16 C = bf16(aux_u16[gi]) + acc
template<int EPI>
__global__ __launch_bounds__(256) void gemm_bt(const u16* __restrict__ A, const u16* __restrict__ B,
                                               void* __restrict__ Cout, const void* __restrict__ aux,
                                               int M, int N, int K){
  const int bz = blockIdx.z;
  const u16* Ab = A + (size_t)bz * M * K;
  const u16* Bb = B + (size_t)bz * N * K;
  const int m0 = blockIdx.y << 7, n0 = blockIdx.x << 7;
  __shared__ __align__(16) u16 As[4096];
  __shared__ __align__(16) u16 Bs[4096];
  const int t = threadIdx.x;
  const int w = t >> 6, l = t & 63;
  const int wr = w >> 1, wc = w & 1;
  const int kofs = (l & 3) << 3;
  const int rA = l >> 2;
  const int aRd = ((wr << 6) + (l & 15)) * 32 + ((l >> 4) << 3);
  const int bRd = ((wc << 6) + (l & 15)) * 32 + ((l >> 4) << 3);
  f32x4 acc[4][4] = {};
  for (int k0 = 0; k0 < K; k0 += 32){
#pragma unroll
    for (int j = 0; j < 2; ++j){
      int rowBase = ((w << 1) + j) << 4;
      load16(&Ab[(size_t)(m0 + rowBase + rA) * K + k0 + kofs], &As[((w << 1) + j) << 9]);
      load16(&Bb[(size_t)(n0 + rowBase + rA) * K + k0 + kofs], &Bs[((w << 1) + j) << 9]);
    }
    __syncthreads();
    bf16x8 aF[4], bF[4];
#pragma unroll
    for (int mf = 0; mf < 4; ++mf) aF[mf] = *(const bf16x8*)&As[aRd + (mf << 9)];
#pragma unroll
    for (int nf = 0; nf < 4; ++nf) bF[nf] = *(const bf16x8*)&Bs[bRd + (nf << 9)];
#pragma unroll
    for (int mf = 0; mf < 4; ++mf)
#pragma unroll
      for (int nf = 0; nf < 4; ++nf)
        acc[mf][nf] = __builtin_amdgcn_mfma_f32_16x16x32_bf16(aF[mf], bF[nf], acc[mf][nf], 0, 0, 0);
    __syncthreads();
  }
#pragma unroll
  for (int mf = 0; mf < 4; ++mf){
#pragma unroll
    for (int nf = 0; nf < 4; ++nf){
      const int col = n0 + (wc << 6) + (nf << 4) + (l & 15);
#pragma unroll
      for (int q = 0; q < 4; ++q){
        const int row = m0 + (wr << 6) + (mf << 4) + ((l >> 4) << 2) + q;
        float v = acc[mf][nf][q];
        size_t gi = ((size_t)bz * M + row) * N + col;
        if (EPI == 2){
          ((u16*)Cout)[gi] = f2bf(v);
        } else if (EPI == 3){
          ((u16*)Cout)[gi] = f2bf((row == col ? 2.0f : 0.0f) - v);
        } else if (EPI == 4){
          ((float*)Cout)[gi] = (row == col ? 1.0f : 0.0f) - v;
        } else if (EPI == 5){
          ((float*)Cout)[gi] = ((const float*)Cout)[gi] - v;
        } else {
          ((u16*)Cout)[gi] = f2bf(bf2f(((const u16*)aux)[gi]) + v);
        }
      }
    }
  }
}

// 256x256-tile bt-form bf16 MFMA gemm, 512 threads (8 waves, 2Mx4N),
// BK=32, 4 LDS K-tile buffers (128 KiB), 3-deep prefetch with counted vmcnt,
// asm s_barrier with memory clobber, LDS XOR-swizzle applied both-sides
// (pre-swizzled global source for linear global_load_lds dest + swizzled
// ds_read), setprio around the MFMA cluster.
// EPI 0: f32 out[row*N+col] = acc + aux[col]                  (aux = bias)
// EPI 1: bf16 out = 2.000001*acc - aux[(bz*512+row)*4096+col] (aux = weight)
template<int EPI>
__global__ __launch_bounds__(512, 2) void gemm256(const u16* __restrict__ A, const u16* __restrict__ B,
                                                  void* __restrict__ Cout, const float* __restrict__ aux,
                                                  int M, int N, int K){
  __shared__ __align__(16) char lds[131072];
  const int bz = blockIdx.z;
  const char* Ab = (const char*)(A + (size_t)bz * M * K);
  const char* Bb = (const char*)(B + (size_t)bz * N * K);
  const int NB = N >> 8;
  const int nwg = gridDim.x;
  const int bid = blockIdx.x;
  const int swzb = (bid & 7) * (nwg >> 3) + (bid >> 3);   // nwg % 8 == 0
  const int m0 = (swzb / NB) << 8;
  const int n0 = (swzb % NB) << 8;
  const int tid = threadIdx.x;
  const int w = tid >> 6, l = tid & 63;
  const int wm = w >> 2, wn = w & 3;
  const size_t Kb = (size_t)K << 1;
  const int NT = K >> 5;
  // staging: thread tid covers linear LDS bytes [tid*16, tid*16+16) of each half;
  // source k-byte pre-swizzled so that LDS[row][kc] = G[row][kc ^ swz(row)],
  // swz(row) = ((row>>1)&3)<<4
  const int sRow = tid >> 2;
  const int sCol = ((tid & 3) << 4) ^ (((tid >> 3) & 3) << 4);
  const char* aSrc0 = Ab + (size_t)(m0 + sRow) * Kb + sCol;
  const char* aSrc1 = Ab + (size_t)(m0 + 128 + sRow) * Kb + sCol;
  const char* bSrc0 = Bb + (size_t)(n0 + sRow) * Kb + sCol;
  const char* bSrc1 = Bb + (size_t)(n0 + 128 + sRow) * Kb + sCol;
  const int dstOff = w << 10;
  // fragment reads: row = wbase + frag*16 + (l&15), k-byte = ((l>>4)*16) ^ swz(row)
  const int swx = ((l >> 1) & 3) << 4;
  const int aRd = ((wm << 7) + (l & 15)) * 64 + (((l >> 4) << 4) ^ swx);
  const int bRd = ((wn << 6) + (l & 15)) * 64 + (((l >> 4) << 4) ^ swx);

#define STAGE(tt) { const int bu = (tt) & 3; const size_t ko = (size_t)(tt) << 6; \
    char* lb = lds + bu * 32768; \
    load16((const u16*)(aSrc0 + ko), (u16*)(lb + dstOff)); \
    load16((const u16*)(aSrc1 + ko), (u16*)(lb + 8192 + dstOff)); \
    load16((const u16*)(bSrc0 + ko), (u16*)(lb + 16384 + dstOff)); \
    load16((const u16*)(bSrc1 + ko), (u16*)(lb + 24576 + dstOff)); }

  f32x4 acc[8][4] = {};
  STAGE(0);
  if (NT > 1) STAGE(1);
  if (NT > 2) STAGE(2);
  for (int t = 0; t < NT; ++t){
    if (t + 3 < NT) STAGE(t + 3);
    const int rem = NT - 1 - t;
    if (rem >= 3)      asm volatile("s_waitcnt vmcnt(12)" ::: "memory");
    else if (rem == 2) asm volatile("s_waitcnt vmcnt(8)" ::: "memory");
    else if (rem == 1) asm volatile("s_waitcnt vmcnt(4)" ::: "memory");
    else               asm volatile("s_waitcnt vmcnt(0)" ::: "memory");
    asm volatile("s_barrier" ::: "memory");   // all waves' parts of tile t landed
    __builtin_amdgcn_sched_barrier(0);
    const char* base = lds + (t & 3) * 32768;
    bf16x8 aF[8], bF[4];
#pragma unroll
    for (int mf = 0; mf < 8; ++mf) aF[mf] = *(const bf16x8*)(base + aRd + (mf << 10));
#pragma unroll
    for (int nf = 0; nf < 4; ++nf) bF[nf] = *(const bf16x8*)(base + 16384 + bRd + (nf << 10));
    __builtin_amdgcn_s_setprio(1);
#pragma unroll
    for (int mf = 0; mf < 8; ++mf)
#pragma unroll
      for (int nf = 0; nf < 4; ++nf)
        acc[mf][nf] = __builtin_amdgcn_mfma_f32_16x16x32_bf16(aF[mf], bF[nf], acc[mf][nf], 0, 0, 0);
    __builtin_amdgcn_s_setprio(0);
    __builtin_amdgcn_sched_barrier(0);        // pin MFMAs (and their lgkm waits) above
    asm volatile("s_barrier" ::: "memory");   // buf[t&3] free for re-stage next iter
  }
#undef STAGE
#pragma unroll
  for (int mf = 0; mf < 8; ++mf){
#pragma unroll
    for (int nf = 0; nf < 4; ++nf){
      const int col = n0 + (wn << 6) + (nf << 4) + (l & 15);
#pragma unroll
      for (int q = 0; q < 4; ++q){
        const int row = m0 + (wm << 7) + (mf << 4) + ((l >> 4) << 2) + q;
        float v = acc[mf][nf][q];
        if (EPI == 0){
          ((float*)Cout)[(size_t)row * N + col] = v + aux[col];
        } else {
          size_t gi = ((size_t)(bz << 9) + row) * 4096 + col;
          ((u16*)Cout)[gi] = f2bf(2.000001f * v - aux[gi]);
        }
      }
    }
  }
}

extern "C" void kernel_launch(void* const* d_in, const int* in_sizes, int n_in,
                              void* d_out, int out_size, void* d_ws, size_t ws_size,
                              hipStream_t stream){
  const float* W    = (const float*)d_in[0];
  const float* bias = (const float*)d_in[1];
  const float* x    = (const float*)d_in[2];
  const float* R    = (const float*)d_in[3];
  (void)in_sizes; (void)n_in; (void)out_size; (void)ws_size;

  char* ws = (char*)d_ws;
  const size_t MiB = (size_t)1 << 20;
  u16*   Mh   = (u16*)(ws + 0 * MiB);    // 4 MiB ; later reused as Xf
  u16*   Ml   = (u16*)(ws + 4 * MiB);    // 4 MiB
  u16*   Xa   = (u16*)(ws + 8 * MiB);    // 4 MiB
  u16*   Xta  = (u16*)(ws + 12 * MiB);   // 4 MiB
  u16*   Xb   = (u16*)(ws + 16 * MiB);   // 4 MiB
  u16*   Xtb  = (u16*)(ws + 20 * MiB);   // 4 MiB
  u16*   Yt   = (u16*)(ws + 24 * MiB);   // 4 MiB ; later reused as Rtb
  float* Rt   = (float*)(ws + 8 * MiB);  // 8 MiB, aliases Xa+Xta (dead by then)
  u16*   Xf   = Mh;                      // final bf16 Minv (Mh dead after refine)
  u16*   Rtb  = Yt;
  u16*   Wt   = (u16*)(ws + 28 * MiB);   // 32 MiB -> [28,60)
  u16*   xbf  = (u16*)(ws + 0 * MiB);    // 64 MiB -> [0,64), aliases NS+Wt (dead by then)
  u16*   filt = (u16*)(ws + 64 * MiB);   // 32 MiB -> [64,96) — DISJOINT from xbf

  const dim3 gNS(4, 4, 8);

  // Phase 1: NS setup (Mh/Ml split + X0/X0t), all bf16
  build_ns<<<8192, 256, 0, stream>>>(R, Mh, Ml, Xa, Xta);
  // Phase 2: 3 bf16 NS iterations maintaining (X, X^T):
  //   Yt = 2I - bt(Xt, Mh); X' = bt(X, Yt); X't = bt(Yt, X)
  gemm_bt<3><<<gNS, 256, 0, stream>>>(Xta, Mh, Yt, nullptr, 512, 512, 512);
  gemm_bt<2><<<gNS, 256, 0, stream>>>(Xa,  Yt, Xb,  nullptr, 512, 512, 512);
  gemm_bt<2><<<gNS, 256, 0, stream>>>(Yt,  Xa, Xtb, nullptr, 512, 512, 512);
  gemm_bt<3><<<gNS, 256, 0, stream>>>(Xtb, Mh, Yt, nullptr, 512, 512, 512);
  gemm_bt<2><<<gNS, 256, 0, stream>>>(Xb,  Yt, Xa,  nullptr, 512, 512, 512);
  gemm_bt<2><<<gNS, 256, 0, stream>>>(Yt,  Xb, Xta, nullptr, 512, 512, 512);
  gemm_bt<3><<<gNS, 256, 0, stream>>>(Xta, Mh, Yt, nullptr, 512, 512, 512);
  gemm_bt<2><<<gNS, 256, 0, stream>>>(Xa,  Yt, Xb,  nullptr, 512, 512, 512);
  gemm_bt<2><<<gNS, 256, 0, stream>>>(Yt,  Xa, Xtb, nullptr, 512, 512, 512);
  // Phase 3: split-precision refinement: Rt = I - bt(X3t, Mh) - bt(X3t, Ml);
  //          Xf = bf16(X3 + bt(X3, bf16(Rt)))
  gemm_bt<4><<<gNS, 256, 0, stream>>>(Xtb, Mh, Rt, nullptr, 512, 512, 512);
  gemm_bt<5><<<gNS, 256, 0, stream>>>(Xtb, Ml, Rt, nullptr, 512, 512, 512);
  conv_bf16<<<1024, 256, 0, stream>>>(Rt, Rtb);
  gemm_bt<6><<<gNS, 256, 0, stream>>>(Xb, Rtb, Xf, Xb, 512, 512, 512);
  // Phase 4: filt = 2.000001 * Minv @ W - W  (bf16 out)
  transpose_w<<<dim3(128, 16, 8), 256, 0, stream>>>(W, Wt);
  gemm256<1><<<dim3(32, 1, 8), 512, 0, stream>>>(Xf, Wt, (void*)filt, W, 512, 4096, 512);
  // Phase 5: x -> bf16 (aliases dead NS/Wt region; filt is PAST 64 MiB)
  conv_bf16<<<16384, 256, 0, stream>>>(x, xbf);
  // Phase 6: out = x @ filt^T + bias
  gemm256<0><<<dim3(512, 1, 1), 512, 0, stream>>>(xbf, filt, d_out, bias, 8192, 4096, 4096);
}

// Round 5
// 428.175 us; speedup vs baseline: 1.9092x; 1.2591x over previous
//
#include <hip/hip_runtime.h>

typedef unsigned short u16;
typedef __attribute__((ext_vector_type(8))) short bf16x8;
typedef __attribute__((ext_vector_type(4))) float f32x4;
typedef __attribute__((ext_vector_type(8))) unsigned short u16x8;
typedef __attribute__((ext_vector_type(4))) unsigned short u16x4;

__device__ __forceinline__ u16 f2bf(float f){
  unsigned int u = __builtin_bit_cast(unsigned int, f);
  u += 0x7FFFu + ((u >> 16) & 1u);
  return (u16)(u >> 16);
}
__device__ __forceinline__ float bf2f(u16 h){
  unsigned int u = ((unsigned int)h) << 16;
  return __builtin_bit_cast(float, u);
}

__device__ __forceinline__ void load16(const u16* g, u16* s){
  __builtin_amdgcn_global_load_lds((const __attribute__((address_space(1))) unsigned int*)g,
                                   (__attribute__((address_space(3))) unsigned int*)s,
                                   16, 0, 0);
}

// From R: S = 0.5(A-A^T). Sbf = bf16(S); Dbf = bf16((c+1)(cI - S)), c=1.000001
__global__ __launch_bounds__(256) void build_s(const float* __restrict__ R, u16* __restrict__ Sbf,
                                               u16* __restrict__ Dbf){
  int idx = blockIdx.x * 256 + threadIdx.x;
  int b = idx >> 18;
  int i = (idx >> 9) & 511;
  int j = idx & 511;
  float a  = R[idx];
  float at = R[(b << 18) + (j << 9) + i];
  float s = 0.5f * (a - at);
  Sbf[idx] = f2bf(s);
  Dbf[idx] = f2bf((i == j ? 2.000003f : 0.0f) - 2.000001f * s);
}

// From f32 P: Ph = bf16(P), Pl = bf16(P - Ph), X1 = bf16(2b I - b^2 P), b=2/2.42
__global__ __launch_bounds__(256) void split_p(const float* __restrict__ P, u16* __restrict__ Ph,
                                               u16* __restrict__ Pl, u16* __restrict__ X1){
  int idx = blockIdx.x * 256 + threadIdx.x;
  int i = (idx >> 9) & 511;
  int j = idx & 511;
  float p = P[idx];
  u16 ph = f2bf(p);
  Ph[idx] = ph;
  Pl[idx] = f2bf(p - bf2f(ph));
  const float beta = 0.8264463f;
  X1[idx] = f2bf((i == j ? 2.0f * beta : 0.0f) - beta * beta * p);
}

// vectorized f32 -> bf16 (8 elems / thread, exact multiple)
__global__ __launch_bounds__(256) void conv_bf16(const float* __restrict__ src, u16* __restrict__ dst){
  size_t i = (size_t)blockIdx.x * 256 + threadIdx.x;
  const float4* s = (const float4*)src + i * 2;
  float4 v0 = s[0], v1 = s[1];
  u16x8 o = { f2bf(v0.x), f2bf(v0.y), f2bf(v0.z), f2bf(v0.w),
              f2bf(v1.x), f2bf(v1.y), f2bf(v1.z), f2bf(v1.w) };
  *(u16x8*)(dst + i * 8) = o;
}

// Wt[b][i][j] = W[b*512 + j][i]  (bf16), i in [0,4096), j in [0,512)
__global__ __launch_bounds__(256) void transpose_w(const float* __restrict__ W, u16* __restrict__ Wt){
  const int b = blockIdx.z;
  const int i0 = blockIdx.x << 5;
  const int j0 = blockIdx.y << 5;
  __shared__ float tile[32][33];
  const int t = threadIdx.x;
  const int r = t >> 3, c = (t & 7) << 2;
  float4 v = *(const float4*)&W[(size_t)((b << 9) + j0 + r) * 4096 + i0 + c];
  tile[r][c+0] = v.x; tile[r][c+1] = v.y; tile[r][c+2] = v.z; tile[r][c+3] = v.w;
  __syncthreads();
  u16x4 o = { f2bf(tile[c+0][r]), f2bf(tile[c+1][r]), f2bf(tile[c+2][r]), f2bf(tile[c+3][r]) };
  *(u16x4*)&Wt[((size_t)b << 21) + (size_t)(i0 + r) * 512 + j0 + c] = o;
}

// 128x128-tile bt-form bf16 MFMA gemm (m97 structure): C[m,n] = sum_k A[m,k]*B[n,k]
// EPI 2: bf16 C = acc
// EPI 3: bf16 C = 2*diag - acc
// EPI 4: f32  C = diag - acc
// EPI 5: f32  C = C - acc          (read-modify-write)
// EPI 6: bf16 C = bf16(aux_u16[gi]) + acc
// EPI 8: f32  C = acc + c^2*diag
// EPI 9: bf16 C = acc - diag
template<int EPI>
__global__ __launch_bounds__(256) void gemm_bt(const u16* __restrict__ A, const u16* __restrict__ B,
                                               void* __restrict__ Cout, const void* __restrict__ aux,
                                               int M, int N, int K){
  const int bz = blockIdx.z;
  const u16* Ab = A + (size_t)bz * M * K;
  const u16* Bb = B + (size_t)bz * N * K;
  const int m0 = blockIdx.y << 7, n0 = blockIdx.x << 7;
  __shared__ __align__(16) u16 As[4096];
  __shared__ __align__(16) u16 Bs[4096];
  const int t = threadIdx.x;
  const int w = t >> 6, l = t & 63;
  const int wr = w >> 1, wc = w & 1;
  const int kofs = (l & 3) << 3;
  const int rA = l >> 2;
  const int aRd = ((wr << 6) + (l & 15)) * 32 + ((l >> 4) << 3);
  const int bRd = ((wc << 6) + (l & 15)) * 32 + ((l >> 4) << 3);
  f32x4 acc[4][4] = {};
  for (int k0 = 0; k0 < K; k0 += 32){
#pragma unroll
    for (int j = 0; j < 2; ++j){
      int rowBase = ((w << 1) + j) << 4;
      load16(&Ab[(size_t)(m0 + rowBase + rA) * K + k0 + kofs], &As[((w << 1) + j) << 9]);
      load16(&Bb[(size_t)(n0 + rowBase + rA) * K + k0 + kofs], &Bs[((w << 1) + j) << 9]);
    }
    __syncthreads();
    bf16x8 aF[4], bF[4];
#pragma unroll
    for (int mf = 0; mf < 4; ++mf) aF[mf] = *(const bf16x8*)&As[aRd + (mf << 9)];
#pragma unroll
    for (int nf = 0; nf < 4; ++nf) bF[nf] = *(const bf16x8*)&Bs[bRd + (nf << 9)];
#pragma unroll
    for (int mf = 0; mf < 4; ++mf)
#pragma unroll
      for (int nf = 0; nf < 4; ++nf)
        acc[mf][nf] = __builtin_amdgcn_mfma_f32_16x16x32_bf16(aF[mf], bF[nf], acc[mf][nf], 0, 0, 0);
    __syncthreads();
  }
#pragma unroll
  for (int mf = 0; mf < 4; ++mf){
#pragma unroll
    for (int nf = 0; nf < 4; ++nf){
      const int col = n0 + (wc << 6) + (nf << 4) + (l & 15);
#pragma unroll
      for (int q = 0; q < 4; ++q){
        const int row = m0 + (wr << 6) + (mf << 4) + ((l >> 4) << 2) + q;
        float v = acc[mf][nf][q];
        size_t gi = ((size_t)bz * M + row) * N + col;
        if (EPI == 2){
          ((u16*)Cout)[gi] = f2bf(v);
        } else if (EPI == 3){
          ((u16*)Cout)[gi] = f2bf((row == col ? 2.0f : 0.0f) - v);
        } else if (EPI == 4){
          ((float*)Cout)[gi] = (row == col ? 1.0f : 0.0f) - v;
        } else if (EPI == 5){
          ((float*)Cout)[gi] = ((const float*)Cout)[gi] - v;
        } else if (EPI == 6){
          ((u16*)Cout)[gi] = f2bf(bf2f(((const u16*)aux)[gi]) + v);
        } else if (EPI == 8){
          ((float*)Cout)[gi] = v + (row == col ? 1.000002f : 0.0f);
        } else {
          ((u16*)Cout)[gi] = f2bf(v - (row == col ? 1.0f : 0.0f));
        }
      }
    }
  }
}

// 256x256-tile bt-form bf16 MFMA gemm, 512 threads (8 waves, 2Mx4N), BK=64,
// 2 LDS K-tile buffers (128 KiB), m201-style 4-phase-per-K-tile schedule:
// each phase = {ds_read register subtile | stage 1 half-tile (2xglobal_load_lds)
//  | barrier | 16 MFMA (one wave-quadrant, setprio-bracketed) | barrier},
// vmcnt(4) once per tile (phase 3) -- loads stay in flight across barriers.
// Snake quadrant order (0,0),(0,1),(1,1),(1,0) reuses A/B register subtiles.
// LDS XOR-swizzle byte^=((row&7)<<4) applied both-sides (pre-swizzled global
// source for linear global_load_lds dest + swizzled ds_read).
// EPI 0: f32 out[row*N+col] = acc + aux[col] (aux = bias) ; EPI 2: bf16 C = acc
template<int EPI>
__global__ __launch_bounds__(512, 2) void gemm256(const u16* __restrict__ A, const u16* __restrict__ B,
                                                  void* __restrict__ Cout, const float* __restrict__ aux,
                                                  int M, int N, int K){
  __shared__ __align__(16) char lds[131072];
  const int bz = blockIdx.z;
  const char* Ab = (const char*)(A + (size_t)bz * M * K);
  const char* Bb = (const char*)(B + (size_t)bz * N * K);
  const int NB = N >> 8;
  const int nwg = gridDim.x;
  const int bid = blockIdx.x;
  const int swzb = (bid & 7) * (nwg >> 3) + (bid >> 3);   // nwg % 8 == 0
  const int m0 = (swzb / NB) << 8;
  const int n0 = (swzb % NB) << 8;
  const int tid = threadIdx.x;
  const int w = tid >> 6, l = tid & 63;
  const int wm = w >> 2, wn = w & 3;
  const size_t Kb = (size_t)K << 1;
  const int NT = K >> 6;
  // staging: thread covers linear LDS bytes [tid*16,+16) of each 8KiB block
  // (64 rows x 128B); source col pre-swizzled by ((row&7)<<4)
  const int sRow = tid >> 3;
  const int sCol = ((tid & 7) << 4) ^ ((sRow & 7) << 4);
  const int sDst = tid << 4;
  const char* aS = Ab + (size_t)(m0 + sRow) * Kb + sCol;
  const char* bS = Bb + (size_t)(n0 + sRow) * Kb + sCol;
  // fragment reads: row = 64*uq + 16*i + (l&15); kbyte = (kk*64 + (l>>4)*16) ^ ((l&7)<<4)
  const int lrow = (l & 15) << 7;
  const int kq0 = (((l >> 4) << 4)) ^ ((l & 7) << 4);
  const int aOff = (wm << 14) + lrow;
  const int bOff = 32768 + ((wn >> 1) << 14) + ((wn & 1) << 13) + lrow;

  // stage half-tile h of matrix (isB) for K-tile tt into buffer (tt&1)
#define STAGE_H(isB, h, tt) { \
    const int _lo = (((tt) & 1) << 16) + ((isB) << 15) + ((h) << 14); \
    const char* _s = ((isB) ? bS : aS) + ((size_t)((h) << 7)) * Kb + ((size_t)(tt) << 7); \
    load16((const u16*)_s, (u16*)(lds + _lo + sDst)); \
    load16((const u16*)(_s + (Kb << 6)), (u16*)(lds + _lo + 8192 + sDst)); }

#define RD_A(bufb, UQ) \
  _Pragma("unroll") for (int i2 = 0; i2 < 4; ++i2){ \
    aF[i2][0] = *(const bf16x8*)(lds + (bufb) + aOff + ((UQ) << 13) + (i2 << 11) + kq0); \
    aF[i2][1] = *(const bf16x8*)(lds + (bufb) + aOff + ((UQ) << 13) + (i2 << 11) + (kq0 ^ 64)); }

#define RD_B(bufb, VQ) \
  _Pragma("unroll") for (int j2 = 0; j2 < 2; ++j2){ \
    bF[VQ][j2][0] = *(const bf16x8*)(lds + (bufb) + bOff + ((VQ) << 12) + (j2 << 11) + kq0); \
    bF[VQ][j2][1] = *(const bf16x8*)(lds + (bufb) + bOff + ((VQ) << 12) + (j2 << 11) + (kq0 ^ 64)); }

#define MFMA16(UQ, VQ) \
    __builtin_amdgcn_s_setprio(1); \
    _Pragma("unroll") for (int i2 = 0; i2 < 4; ++i2) \
      _Pragma("unroll") for (int j2 = 0; j2 < 2; ++j2){ \
        acc[(UQ)*4+i2][(VQ)*2+j2] = __builtin_amdgcn_mfma_f32_16x16x32_bf16(aF[i2][0], bF[VQ][j2][0], acc[(UQ)*4+i2][(VQ)*2+j2], 0, 0, 0); \
        acc[(UQ)*4+i2][(VQ)*2+j2] = __builtin_amdgcn_mfma_f32_16x16x32_bf16(aF[i2][1], bF[VQ][j2][1], acc[(UQ)*4+i2][(VQ)*2+j2], 0, 0, 0); } \
    __builtin_amdgcn_s_setprio(0); \
    __builtin_amdgcn_sched_barrier(0);

#define BAR asm volatile("s_barrier" ::: "memory");
#define VM4 asm volatile("s_waitcnt vmcnt(4)" ::: "memory");

  bf16x8 aF[4][2], bF[2][2][2];
  f32x4 acc[8][4] = {};

  // prologue: steady-state issue order A0(0),B0(0),A1(0),B1(0),A0(1),B0(1)
  STAGE_H(0,0,0) STAGE_H(1,0,0) STAGE_H(0,1,0) STAGE_H(1,1,0)
  STAGE_H(0,0,1) STAGE_H(1,0,1)
  VM4 BAR

#define KTILE(t, bufb) { \
    const int t1 = ((t)+1 < NT) ? (t)+1 : NT-1; \
    const int t2 = ((t)+2 < NT) ? (t)+2 : NT-1; \
    RD_A(bufb, 0) RD_B(bufb, 0) STAGE_H(0,1,t1) BAR MFMA16(0,0) BAR \
    RD_B(bufb, 1)               STAGE_H(1,1,t1) BAR MFMA16(0,1) BAR \
    RD_A(bufb, 1)               STAGE_H(0,0,t2) BAR MFMA16(1,1) BAR \
                                STAGE_H(1,0,t2) VM4 BAR MFMA16(1,0) BAR }

#pragma unroll 1
  for (int tp = 0; tp < NT; tp += 2){
    KTILE(tp, 0)
    KTILE(tp+1, 65536)
  }
#undef KTILE
#undef STAGE_H
#undef RD_A
#undef RD_B
#undef MFMA16
#undef BAR
#undef VM4

#pragma unroll
  for (int mf = 0; mf < 8; ++mf){
#pragma unroll
    for (int nf = 0; nf < 4; ++nf){
      const int col = n0 + (wn << 6) + (nf << 4) + (l & 15);
#pragma unroll
      for (int q = 0; q < 4; ++q){
        const int row = m0 + (wm << 7) + (mf << 4) + ((l >> 4) << 2) + q;
        float v = acc[mf][nf][q];
        if (EPI == 0){
          ((float*)Cout)[(size_t)row * N + col] = v + aux[col];
        } else {
          ((u16*)Cout)[((size_t)bz * M + row) * N + col] = f2bf(v);
        }
      }
    }
  }
}

extern "C" void kernel_launch(void* const* d_in, const int* in_sizes, int n_in,
                              void* d_out, int out_size, void* d_ws, size_t ws_size,
                              hipStream_t stream){
  const float* W    = (const float*)d_in[0];
  const float* bias = (const float*)d_in[1];
  const float* x    = (const float*)d_in[2];
  const float* R    = (const float*)d_in[3];
  (void)in_sizes; (void)n_in; (void)out_size; (void)ws_size;

  char* ws = (char*)d_ws;
  const size_t MiB = (size_t)1 << 20;
  u16*   Sbf  = (u16*)(ws + 0 * MiB);    // 4 MiB ; later reused as G
  u16*   Dbf  = (u16*)(ws + 4 * MiB);    // 4 MiB
  float* Pf   = (float*)(ws + 8 * MiB);  // 8 MiB ; later reused as Rf
  u16*   Ph   = (u16*)(ws + 16 * MiB);   // 4 MiB
  u16*   Pl   = (u16*)(ws + 20 * MiB);   // 4 MiB
  u16*   X1   = (u16*)(ws + 24 * MiB);   // 4 MiB ; later reused as Rbf
  u16*   Ybf  = (u16*)(ws + 28 * MiB);   // 4 MiB ; later reused as X3
  u16*   X2   = (u16*)(ws + 32 * MiB);   // 4 MiB
  float* Rf   = Pf;
  u16*   Rbf  = X1;
  u16*   X3   = Ybf;
  u16*   G    = Sbf;
  u16*   Wt   = (u16*)(ws + 36 * MiB);   // 32 MiB -> [36,68)
  u16*   filt = (u16*)(ws + 68 * MiB);   // 32 MiB -> [68,100)
  u16*   xbf  = (u16*)(ws + 0 * MiB);    // 64 MiB -> [0,64), aliases NS+Wt (dead by then)

  const dim3 gNS(4, 4, 8);

  // Phase 1: S (bf16) and D = (c+1)(cI - S) (bf16)
  build_s<<<8192, 256, 0, stream>>>(R, Sbf, Dbf);
  // Phase 2: P = c^2 I + S S^T  (SPD; all NS iterates symmetric -> bt == plain product)
  gemm_bt<8><<<gNS, 256, 0, stream>>>(Sbf, Sbf, Pf, nullptr, 512, 512, 512);
  // Phase 3: split P -> Ph+Pl; closed-form first NS iterate X1 = b(2I - bP)
  split_p<<<8192, 256, 0, stream>>>(Pf, Ph, Pl, X1);
  // Phase 4: one NS iteration: Y = 2I - Ph X1 ; X2 = X1 Y
  gemm_bt<3><<<gNS, 256, 0, stream>>>(Ph, X1, Ybf, nullptr, 512, 512, 512);
  gemm_bt<2><<<gNS, 256, 0, stream>>>(X1, Ybf, X2, nullptr, 512, 512, 512);
  // Phase 5: split-precision refinement: R = I - (Ph+Pl) X2 ; X3 = X2 + X2 R
  gemm_bt<4><<<gNS, 256, 0, stream>>>(Ph, X2, Rf, nullptr, 512, 512, 512);
  gemm_bt<5><<<gNS, 256, 0, stream>>>(Pl, X2, Rf, nullptr, 512, 512, 512);
  conv_bf16<<<1024, 256, 0, stream>>>(Rf, Rbf);
  gemm_bt<6><<<gNS, 256, 0, stream>>>(X2, Rbf, X3, X2, 512, 512, 512);
  // Phase 6: G = Q = D Pinv - I  (bf16)
  gemm_bt<9><<<gNS, 256, 0, stream>>>(Dbf, X3, G, nullptr, 512, 512, 512);
  // Phase 7: filt = G @ Wb  (bf16 out, plain store)
  transpose_w<<<dim3(128, 16, 8), 256, 0, stream>>>(W, Wt);
  gemm256<2><<<dim3(32, 1, 8), 512, 0, stream>>>(G, Wt, (void*)filt, nullptr, 512, 4096, 512);
  // Phase 8: x -> bf16 (aliases dead NS/Wt region; filt is past 68 MiB)
  conv_bf16<<<16384, 256, 0, stream>>>(x, xbf);
  // Phase 9: out = x @ filt^T + bias
  gemm256<0><<<dim3(512, 1, 1), 512, 0, stream>>>(xbf, filt, d_out, bias, 8192, 4096, 4096);
}

// Round 6
// 412.016 us; speedup vs baseline: 1.9840x; 1.0392x over previous
//
#include <hip/hip_runtime.h>

typedef unsigned short u16;
typedef __attribute__((ext_vector_type(8))) short bf16x8;
typedef __attribute__((ext_vector_type(4))) float f32x4;
typedef __attribute__((ext_vector_type(8))) unsigned short u16x8;
typedef __attribute__((ext_vector_type(4))) unsigned short u16x4;

__device__ __forceinline__ u16 f2bf(float f){
  unsigned int u = __builtin_bit_cast(unsigned int, f);
  u += 0x7FFFu + ((u >> 16) & 1u);
  return (u16)(u >> 16);
}
__device__ __forceinline__ float bf2f(u16 h){
  unsigned int u = ((unsigned int)h) << 16;
  return __builtin_bit_cast(float, u);
}

__device__ __forceinline__ void load16(const u16* g, u16* s){
  __builtin_amdgcn_global_load_lds((const __attribute__((address_space(1))) unsigned int*)g,
                                   (__attribute__((address_space(3))) unsigned int*)s,
                                   16, 0, 0);
}

// From R: S = 0.5(A-A^T). Sbf = bf16(S); Dbf = bf16((c+1)(cI - S)), c=1.000001
__global__ __launch_bounds__(256) void build_s(const float* __restrict__ R, u16* __restrict__ Sbf,
                                               u16* __restrict__ Dbf){
  int idx = blockIdx.x * 256 + threadIdx.x;
  int b = idx >> 18;
  int i = (idx >> 9) & 511;
  int j = idx & 511;
  float a  = R[idx];
  float at = R[(b << 18) + (j << 9) + i];
  float s = 0.5f * (a - at);
  Sbf[idx] = f2bf(s);
  Dbf[idx] = f2bf((i == j ? 2.000003f : 0.0f) - 2.000001f * s);
}

// From f32 P: Phl = [bf16(P) | bf16(P - Ph)] (K-concat, width 1024);
// X1 = bf16(2b I - b^2 P), b = 2/2.42; X1d = [X1 | X1] (width 1024)
__global__ __launch_bounds__(256) void split_p(const float* __restrict__ P, u16* __restrict__ Phl,
                                               u16* __restrict__ X1, u16* __restrict__ X1d){
  int idx = blockIdx.x * 256 + threadIdx.x;
  int i = (idx >> 9) & 511;   // row within block (idx = (b*512+i)*512 + j)
  int j = idx & 511;
  float p = P[idx];
  u16 ph = f2bf(p);
  size_t rb = ((size_t)(idx >> 9)) << 10;   // (b*512+i)*1024
  Phl[rb + j]       = ph;
  Phl[rb + 512 + j] = f2bf(p - bf2f(ph));
  const float beta = 0.8264463f;
  u16 x1 = f2bf((i == j ? 2.0f * beta : 0.0f) - beta * beta * p);
  X1[idx] = x1;
  X1d[rb + j]       = x1;
  X1d[rb + 512 + j] = x1;
}

// vectorized f32 -> bf16 (8 elems / thread, exact multiple)
__global__ __launch_bounds__(256) void conv_bf16(const float* __restrict__ src, u16* __restrict__ dst){
  size_t i = (size_t)blockIdx.x * 256 + threadIdx.x;
  const float4* s = (const float4*)src + i * 2;
  float4 v0 = s[0], v1 = s[1];
  u16x8 o = { f2bf(v0.x), f2bf(v0.y), f2bf(v0.z), f2bf(v0.w),
              f2bf(v1.x), f2bf(v1.y), f2bf(v1.z), f2bf(v1.w) };
  *(u16x8*)(dst + i * 8) = o;
}

// Wt[b][i][j] = W[b*512 + j][i]  (bf16), i in [0,4096), j in [0,512)
__global__ __launch_bounds__(256) void transpose_w(const float* __restrict__ W, u16* __restrict__ Wt){
  const int b = blockIdx.z;
  const int i0 = blockIdx.x << 5;
  const int j0 = blockIdx.y << 5;
  __shared__ float tile[32][33];
  const int t = threadIdx.x;
  const int r = t >> 3, c = (t & 7) << 2;
  float4 v = *(const float4*)&W[(size_t)((b << 9) + j0 + r) * 4096 + i0 + c];
  tile[r][c+0] = v.x; tile[r][c+1] = v.y; tile[r][c+2] = v.z; tile[r][c+3] = v.w;
  __syncthreads();
  u16x4 o = { f2bf(tile[c+0][r]), f2bf(tile[c+1][r]), f2bf(tile[c+2][r]), f2bf(tile[c+3][r]) };
  *(u16x4*)&Wt[((size_t)b << 21) + (size_t)(i0 + r) * 512 + j0 + c] = o;
}

// 128x128-tile bt-form bf16 MFMA gemm (m97 structure): C[m,n] = sum_k A[m,k]*B[n,k]
// EPI 2: bf16 C = acc
// EPI 3: bf16 C = 2*diag - acc
// EPI 6: bf16 C = bf16(aux_u16[gi]) + acc
// EPI 7: bf16 C = acc ; also dup into aux (u16, width 1024) at [row][col] and [row][col+512]
// EPI 8: f32  C = acc + c^2*diag
// EPI 9: bf16 C = acc - diag
// EPI 10: bf16 C = diag - acc
template<int EPI>
__global__ __launch_bounds__(256) void gemm_bt(const u16* __restrict__ A, const u16* __restrict__ B,
                                               void* __restrict__ Cout, const void* __restrict__ aux,
                                               int M, int N, int K){
  const int bz = blockIdx.z;
  const u16* Ab = A + (size_t)bz * M * K;
  const u16* Bb = B + (size_t)bz * N * K;
  const int m0 = blockIdx.y << 7, n0 = blockIdx.x << 7;
  __shared__ __align__(16) u16 As[4096];
  __shared__ __align__(16) u16 Bs[4096];
  const int t = threadIdx.x;
  const int w = t >> 6, l = t & 63;
  const int wr = w >> 1, wc = w & 1;
  const int kofs = (l & 3) << 3;
  const int rA = l >> 2;
  const int aRd = ((wr << 6) + (l & 15)) * 32 + ((l >> 4) << 3);
  const int bRd = ((wc << 6) + (l & 15)) * 32 + ((l >> 4) << 3);
  f32x4 acc[4][4] = {};
  for (int k0 = 0; k0 < K; k0 += 32){
#pragma unroll
    for (int j = 0; j < 2; ++j){
      int rowBase = ((w << 1) + j) << 4;
      load16(&Ab[(size_t)(m0 + rowBase + rA) * K + k0 + kofs], &As[((w << 1) + j) << 9]);
      load16(&Bb[(size_t)(n0 + rowBase + rA) * K + k0 + kofs], &Bs[((w << 1) + j) << 9]);
    }
    __syncthreads();
    bf16x8 aF[4], bF[4];
#pragma unroll
    for (int mf = 0; mf < 4; ++mf) aF[mf] = *(const bf16x8*)&As[aRd + (mf << 9)];
#pragma unroll
    for (int nf = 0; nf < 4; ++nf) bF[nf] = *(const bf16x8*)&Bs[bRd + (nf << 9)];
#pragma unroll
    for (int mf = 0; mf < 4; ++mf)
#pragma unroll
      for (int nf = 0; nf < 4; ++nf)
        acc[mf][nf] = __builtin_amdgcn_mfma_f32_16x16x32_bf16(aF[mf], bF[nf], acc[mf][nf], 0, 0, 0);
    __syncthreads();
  }
#pragma unroll
  for (int mf = 0; mf < 4; ++mf){
#pragma unroll
    for (int nf = 0; nf < 4; ++nf){
      const int col = n0 + (wc << 6) + (nf << 4) + (l & 15);
#pragma unroll
      for (int q = 0; q < 4; ++q){
        const int row = m0 + (wr << 6) + (mf << 4) + ((l >> 4) << 2) + q;
        float v = acc[mf][nf][q];
        size_t gi = ((size_t)bz * M + row) * N + col;
        if (EPI == 2){
          ((u16*)Cout)[gi] = f2bf(v);
        } else if (EPI == 3){
          ((u16*)Cout)[gi] = f2bf((row == col ? 2.0f : 0.0f) - v);
        } else if (EPI == 6){
          ((u16*)Cout)[gi] = f2bf(bf2f(((const u16*)aux)[gi]) + v);
        } else if (EPI == 7){
          u16 o = f2bf(v);
          ((u16*)Cout)[gi] = o;
          size_t g2 = (((size_t)bz * M + row) << 10) + col;
          u16* d = (u16*)const_cast<void*>(aux);
          d[g2] = o;
          d[g2 + 512] = o;
        } else if (EPI == 8){
          ((float*)Cout)[gi] = v + (row == col ? 1.000002f : 0.0f);
        } else if (EPI == 9){
          ((u16*)Cout)[gi] = f2bf(v - (row == col ? 1.0f : 0.0f));
        } else {
          ((u16*)Cout)[gi] = f2bf((row == col ? 1.0f : 0.0f) - v);
        }
      }
    }
  }
}

// 256x256-tile bt-form bf16 MFMA gemm, 512 threads (8 waves, 2Mx4N), BK=64,
// 2 LDS K-tile buffers (128 KiB). ONE barrier per K-tile: all ds_reads and
// the 64 MFMAs of a tile run unfenced (compiler pipelines via lgkmcnt; every
// ds_read has a dependent MFMA before the tile-end barrier, so reads drain
// before any wave crosses it -> staging into the other buffer is race-free).
// Counted vmcnt(4) keeps the next tile's late half-stages in flight.
// LDS XOR-swizzle byte^=((row&7)<<4) applied both-sides.
// EPI 0: f32 out[row*N+col] = acc + aux[col] (aux = bias) ; EPI 2: bf16 C = acc
template<int EPI>
__global__ __launch_bounds__(512, 2) void gemm256(const u16* __restrict__ A, const u16* __restrict__ B,
                                                  void* __restrict__ Cout, const float* __restrict__ aux,
                                                  int M, int N, int K){
  __shared__ __align__(16) char lds[131072];
  const int bz = blockIdx.z;
  const char* Ab = (const char*)(A + (size_t)bz * M * K);
  const char* Bb = (const char*)(B + (size_t)bz * N * K);
  const int NB = N >> 8;
  const int nwg = gridDim.x;
  const int bid = blockIdx.x;
  const int swzb = (bid & 7) * (nwg >> 3) + (bid >> 3);   // nwg % 8 == 0
  const int m0 = (swzb / NB) << 8;
  const int n0 = (swzb % NB) << 8;
  const int tid = threadIdx.x;
  const int w = tid >> 6, l = tid & 63;
  const int wm = w >> 2, wn = w & 3;
  const size_t Kb = (size_t)K << 1;
  const int NT = K >> 6;
  const int sRow = tid >> 3;
  const int sCol = ((tid & 7) << 4) ^ ((sRow & 7) << 4);
  const int sDst = tid << 4;
  const char* aS = Ab + (size_t)(m0 + sRow) * Kb + sCol;
  const char* bS = Bb + (size_t)(n0 + sRow) * Kb + sCol;
  const int lrow = (l & 15) << 7;
  const int kq0 = (((l >> 4) << 4)) ^ ((l & 7) << 4);
  const int aOff = (wm << 14) + lrow;
  const int bOff = 32768 + ((wn >> 1) << 14) + ((wn & 1) << 13) + lrow;

#define STAGE_H(isB, h, tt) { \
    const int _lo = (((tt) & 1) << 16) + ((isB) << 15) + ((h) << 14); \
    const char* _s = ((isB) ? bS : aS) + ((size_t)((h) << 7)) * Kb + ((size_t)(tt) << 7); \
    load16((const u16*)_s, (u16*)(lds + _lo + sDst)); \
    load16((const u16*)(_s + (Kb << 6)), (u16*)(lds + _lo + 8192 + sDst)); }

#define RD_A(bufb, UQ) \
  _Pragma("unroll") for (int i2 = 0; i2 < 4; ++i2){ \
    aF[i2][0] = *(const bf16x8*)(lds + (bufb) + aOff + ((UQ) << 13) + (i2 << 11) + kq0); \
    aF[i2][1] = *(const bf16x8*)(lds + (bufb) + aOff + ((UQ) << 13) + (i2 << 11) + (kq0 ^ 64)); }

#define RD_B(bufb, VQ) \
  _Pragma("unroll") for (int j2 = 0; j2 < 2; ++j2){ \
    bF[VQ][j2][0] = *(const bf16x8*)(lds + (bufb) + bOff + ((VQ) << 12) + (j2 << 11) + kq0); \
    bF[VQ][j2][1] = *(const bf16x8*)(lds + (bufb) + bOff + ((VQ) << 12) + (j2 << 11) + (kq0 ^ 64)); }

#define MFMA16(UQ, VQ) \
    _Pragma("unroll") for (int i2 = 0; i2 < 4; ++i2) \
      _Pragma("unroll") for (int j2 = 0; j2 < 2; ++j2){ \
        acc[(UQ)*4+i2][(VQ)*2+j2] = __builtin_amdgcn_mfma_f32_16x16x32_bf16(aF[i2][0], bF[VQ][j2][0], acc[(UQ)*4+i2][(VQ)*2+j2], 0, 0, 0); \
        acc[(UQ)*4+i2][(VQ)*2+j2] = __builtin_amdgcn_mfma_f32_16x16x32_bf16(aF[i2][1], bF[VQ][j2][1], acc[(UQ)*4+i2][(VQ)*2+j2], 0, 0, 0); }

#define BAR asm volatile("s_barrier" ::: "memory");
#define VM4 asm volatile("s_waitcnt vmcnt(4)" ::: "memory");
#define VM0 asm volatile("s_waitcnt vmcnt(0)" ::: "memory");

  bf16x8 aF[4][2], bF[2][2][2];
  f32x4 acc[8][4] = {};

  // prologue: tile 0 fully + tile 1's first halves (order matches steady state)
  STAGE_H(0,0,0) STAGE_H(1,0,0) STAGE_H(0,1,0) STAGE_H(1,1,0)
  STAGE_H(0,0,1) STAGE_H(1,0,1)
  VM4 BAR

  // one barrier per K-tile; ds_reads/MFMAs/stages free-run within the tile
#define KTILE(t, bufb) { \
    const int t1 = ((t)+1 < NT) ? (t)+1 : NT-1; \
    const int t2 = ((t)+2 < NT) ? (t)+2 : NT-1; \
    RD_A(bufb, 0) RD_B(bufb, 0) STAGE_H(0,1,t1) \
    MFMA16(0,0) \
    RD_B(bufb, 1) STAGE_H(1,1,t1) \
    MFMA16(0,1) \
    RD_A(bufb, 1) STAGE_H(0,0,t2) \
    MFMA16(1,1) \
    STAGE_H(1,0,t2) \
    MFMA16(1,0) \
    __builtin_amdgcn_sched_barrier(0); \
    VM4 BAR }

#pragma unroll 1
  for (int tp = 0; tp < NT; tp += 2){
    KTILE(tp, 0)
    KTILE(tp+1, 65536)
  }
  VM0
#undef KTILE
#undef STAGE_H
#undef RD_A
#undef RD_B
#undef MFMA16
#undef BAR
#undef VM4
#undef VM0

#pragma unroll
  for (int mf = 0; mf < 8; ++mf){
#pragma unroll
    for (int nf = 0; nf < 4; ++nf){
      const int col = n0 + (wn << 6) + (nf << 4) + (l & 15);
#pragma unroll
      for (int q = 0; q < 4; ++q){
        const int row = m0 + (wm << 7) + (mf << 4) + ((l >> 4) << 2) + q;
        float v = acc[mf][nf][q];
        if (EPI == 0){
          ((float*)Cout)[(size_t)row * N + col] = v + aux[col];
        } else {
          ((u16*)Cout)[((size_t)bz * M + row) * N + col] = f2bf(v);
        }
      }
    }
  }
}

extern "C" void kernel_launch(void* const* d_in, const int* in_sizes, int n_in,
                              void* d_out, int out_size, void* d_ws, size_t ws_size,
                              hipStream_t stream){
  const float* W    = (const float*)d_in[0];
  const float* bias = (const float*)d_in[1];
  const float* x    = (const float*)d_in[2];
  const float* R    = (const float*)d_in[3];
  (void)in_sizes; (void)n_in; (void)out_size; (void)ws_size;

  char* ws = (char*)d_ws;
  const size_t MiB = (size_t)1 << 20;
  u16*   Sbf  = (u16*)(ws + 0 * MiB);    // 4 MiB ; reused as G
  u16*   Dbf  = (u16*)(ws + 4 * MiB);    // 4 MiB
  float* Pf   = (float*)(ws + 8 * MiB);  // 8 MiB (f32)
  u16*   X1   = (u16*)(ws + 16 * MiB);   // 4 MiB ; reused as Rbf
  u16*   Ybf  = (u16*)(ws + 20 * MiB);   // 4 MiB ; reused as X3
  u16*   X2   = (u16*)(ws + 24 * MiB);   // 4 MiB
  u16*   Phl  = (u16*)(ws + 28 * MiB);   // 8 MiB  [Ph | Pl] width-1024
  u16*   X2d  = (u16*)(ws + 36 * MiB);   // 8 MiB  [X2 | X2] width-1024
  u16*   X1d  = (u16*)(ws + 44 * MiB);   // 8 MiB  [X1 | X1] width-1024
  u16*   Rbf  = X1;
  u16*   X3   = Ybf;
  u16*   G    = Sbf;
  u16*   Wt   = (u16*)(ws + 8 * MiB);    // 32 MiB [8,40) — all NS temps there dead by then
  u16*   filt = (u16*)(ws + 64 * MiB);   // 32 MiB [64,96) — disjoint from xbf
  u16*   xbf  = (u16*)(ws + 0 * MiB);    // 64 MiB [0,64) — everything there dead by then

  const dim3 gNS(4, 4, 8);

  // Phase 1: S (bf16) and D = (c+1)(cI - S)
  build_s<<<8192, 256, 0, stream>>>(R, Sbf, Dbf);
  // Phase 2: P = c^2 I + S S^T (SPD; all NS iterates are polynomials in P -> symmetric)
  gemm_bt<8><<<gNS, 256, 0, stream>>>(Sbf, Sbf, Pf, nullptr, 512, 512, 512);
  // Phase 3: split P -> Phl; X1 = b(2I - bP); X1d dup
  split_p<<<8192, 256, 0, stream>>>(Pf, Phl, X1, X1d);
  // Phase 4: Y = 2I - (Ph+Pl) X1  (one K=1024 gemm, full-precision P)
  gemm_bt<3><<<gNS, 256, 0, stream>>>(Phl, X1d, Ybf, nullptr, 512, 512, 1024);
  // Phase 5: X2 = X1 Y (+ dup into X2d)
  gemm_bt<7><<<gNS, 256, 0, stream>>>(X1, Ybf, X2, X2d, 512, 512, 512);
  // Phase 6: R = I - (Ph+Pl) X2  (one K=1024 gemm, bf16 out)
  gemm_bt<10><<<gNS, 256, 0, stream>>>(Phl, X2d, Rbf, nullptr, 512, 512, 1024);
  // Phase 7: X3 = X2 + X2 R
  gemm_bt<6><<<gNS, 256, 0, stream>>>(X2, Rbf, X3, X2, 512, 512, 512);
  // Phase 8: G = Q = D Pinv - I
  gemm_bt<9><<<gNS, 256, 0, stream>>>(Dbf, X3, G, nullptr, 512, 512, 512);
  // Phase 9: filt = G @ Wb (bf16)
  transpose_w<<<dim3(128, 16, 8), 256, 0, stream>>>(W, Wt);
  gemm256<2><<<dim3(32, 1, 8), 512, 0, stream>>>(G, Wt, (void*)filt, nullptr, 512, 4096, 512);
  // Phase 10: x -> bf16
  conv_bf16<<<16384, 256, 0, stream>>>(x, xbf);
  // Phase 11: out = x @ filt^T + bias
  gemm256<0><<<dim3(512, 1, 1), 512, 0, stream>>>(xbf, filt, d_out, bias, 8192, 4096, 4096);
}

// Round 9
// 410.454 us; speedup vs baseline: 1.9916x; 1.0038x over previous
//
#include <hip/hip_runtime.h>

typedef unsigned short u16;
typedef __attribute__((ext_vector_type(8))) short bf16x8;
typedef __attribute__((ext_vector_type(4))) float f32x4;
typedef __attribute__((ext_vector_type(8))) unsigned short u16x8;
typedef __attribute__((ext_vector_type(4))) unsigned short u16x4;

__device__ __forceinline__ u16 f2bf(float f){
  unsigned int u = __builtin_bit_cast(unsigned int, f);
  u += 0x7FFFu + ((u >> 16) & 1u);
  return (u16)(u >> 16);
}
__device__ __forceinline__ float bf2f(u16 h){
  unsigned int u = ((unsigned int)h) << 16;
  return __builtin_bit_cast(float, u);
}

__device__ __forceinline__ void load16(const u16* g, u16* s){
  __builtin_amdgcn_global_load_lds((const __attribute__((address_space(1))) unsigned int*)g,
                                   (__attribute__((address_space(3))) unsigned int*)s,
                                   16, 0, 0);
}

// From R: S = 0.5(A-A^T). Sbf = bf16(S); Dbf = bf16((c+1)(cI - S)), c=1.000001
__global__ __launch_bounds__(256) void build_s(const float* __restrict__ R, u16* __restrict__ Sbf,
                                               u16* __restrict__ Dbf){
  int idx = blockIdx.x * 256 + threadIdx.x;
  int b = idx >> 18;
  int i = (idx >> 9) & 511;
  int j = idx & 511;
  float a  = R[idx];
  float at = R[(b << 18) + (j << 9) + i];
  float s = 0.5f * (a - at);
  Sbf[idx] = f2bf(s);
  Dbf[idx] = f2bf((i == j ? 2.000003f : 0.0f) - 2.000001f * s);
}

// vectorized f32 -> bf16 (8 elems / thread, exact multiple)
__global__ __launch_bounds__(256) void conv_bf16(const float* __restrict__ src, u16* __restrict__ dst){
  size_t i = (size_t)blockIdx.x * 256 + threadIdx.x;
  const float4* s = (const float4*)src + i * 2;
  float4 v0 = s[0], v1 = s[1];
  u16x8 o = { f2bf(v0.x), f2bf(v0.y), f2bf(v0.z), f2bf(v0.w),
              f2bf(v1.x), f2bf(v1.y), f2bf(v1.z), f2bf(v1.w) };
  *(u16x8*)(dst + i * 8) = o;
}

// Wt[b][i][j] = W[b*512 + j][i]  (bf16), i in [0,4096), j in [0,512)
__global__ __launch_bounds__(256) void transpose_w(const float* __restrict__ W, u16* __restrict__ Wt){
  const int b = blockIdx.z;
  const int i0 = blockIdx.x << 5;
  const int j0 = blockIdx.y << 5;
  __shared__ float tile[32][33];
  const int t = threadIdx.x;
  const int r = t >> 3, c = (t & 7) << 2;
  float4 v = *(const float4*)&W[(size_t)((b << 9) + j0 + r) * 4096 + i0 + c];
  tile[r][c+0] = v.x; tile[r][c+1] = v.y; tile[r][c+2] = v.z; tile[r][c+3] = v.w;
  __syncthreads();
  u16x4 o = { f2bf(tile[c+0][r]), f2bf(tile[c+1][r]), f2bf(tile[c+2][r]), f2bf(tile[c+3][r]) };
  *(u16x4*)&Wt[((size_t)b << 21) + (size_t)(i0 + r) * 512 + j0 + c] = o;
}

// 128x128-tile bt-form bf16 MFMA gemm (m97 structure, PROVEN rounds 1-6):
// C[m,n] = sum_k A[m,k]*B[n,k], batched over blockIdx.z.
// EPI 3:  bf16 C = 2*diag - acc
// EPI 6:  bf16 C = bf16(aux_u16[gi]) + acc
// EPI 7:  bf16 C = acc ; also dup into aux (width 1024) at [row][col], [row][col+512]
// EPI 9:  bf16 C = acc - diag
// EPI 10: bf16 C = diag - acc
// EPI 11: p = acc + c^2*diag (f32): Cout(width1024)=[bf16(p)|bf16(p-ph)];
//         x1 = bf16(2b*diag - b^2*p) -> aux (width 512) and aux2 (width 1024, dup)
template<int EPI>
__global__ __launch_bounds__(256) void gemm_bt(const u16* __restrict__ A, const u16* __restrict__ B,
                                               void* __restrict__ Cout, const void* __restrict__ aux,
                                               void* __restrict__ aux2,
                                               int M, int N, int K){
  const int bz = blockIdx.z;
  const u16* Ab = A + (size_t)bz * M * K;
  const u16* Bb = B + (size_t)bz * N * K;
  const int m0 = blockIdx.y << 7, n0 = blockIdx.x << 7;
  __shared__ __align__(16) u16 As[4096];
  __shared__ __align__(16) u16 Bs[4096];
  const int t = threadIdx.x;
  const int w = t >> 6, l = t & 63;
  const int wr = w >> 1, wc = w & 1;
  const int kofs = (l & 3) << 3;
  const int rA = l >> 2;
  const int aRd = ((wr << 6) + (l & 15)) * 32 + ((l >> 4) << 3);
  const int bRd = ((wc << 6) + (l & 15)) * 32 + ((l >> 4) << 3);
  f32x4 acc[4][4] = {};
  for (int k0 = 0; k0 < K; k0 += 32){
#pragma unroll
    for (int j = 0; j < 2; ++j){
      int rowBase = ((w << 1) + j) << 4;
      load16(&Ab[(size_t)(m0 + rowBase + rA) * K + k0 + kofs], &As[((w << 1) + j) << 9]);
      load16(&Bb[(size_t)(n0 + rowBase + rA) * K + k0 + kofs], &Bs[((w << 1) + j) << 9]);
    }
    __syncthreads();
    bf16x8 aF[4], bF[4];
#pragma unroll
    for (int mf = 0; mf < 4; ++mf) aF[mf] = *(const bf16x8*)&As[aRd + (mf << 9)];
#pragma unroll
    for (int nf = 0; nf < 4; ++nf) bF[nf] = *(const bf16x8*)&Bs[bRd + (nf << 9)];
#pragma unroll
    for (int mf = 0; mf < 4; ++mf)
#pragma unroll
      for (int nf = 0; nf < 4; ++nf)
        acc[mf][nf] = __builtin_amdgcn_mfma_f32_16x16x32_bf16(aF[mf], bF[nf], acc[mf][nf], 0, 0, 0);
    __syncthreads();
  }
#pragma unroll
  for (int mf = 0; mf < 4; ++mf){
#pragma unroll
    for (int nf = 0; nf < 4; ++nf){
      const int col = n0 + (wc << 6) + (nf << 4) + (l & 15);
#pragma unroll
      for (int q = 0; q < 4; ++q){
        const int row = m0 + (wr << 6) + (mf << 4) + ((l >> 4) << 2) + q;
        float v = acc[mf][nf][q];
        size_t gi = ((size_t)bz * M + row) * N + col;
        size_t g2 = (((size_t)bz * M + row) << 10) + col;
        if (EPI == 3){
          ((u16*)Cout)[gi] = f2bf((row == col ? 2.0f : 0.0f) - v);
        } else if (EPI == 6){
          ((u16*)Cout)[gi] = f2bf(bf2f(((const u16*)aux)[gi]) + v);
        } else if (EPI == 7){
          u16 o = f2bf(v);
          ((u16*)Cout)[gi] = o;
          u16* d = (u16*)const_cast<void*>(aux);
          d[g2] = o;
          d[g2 + 512] = o;
        } else if (EPI == 9){
          ((u16*)Cout)[gi] = f2bf(v - (row == col ? 1.0f : 0.0f));
        } else if (EPI == 10){
          ((u16*)Cout)[gi] = f2bf((row == col ? 1.0f : 0.0f) - v);
        } else {  // EPI 11: fused P-split + closed-form first NS iterate
          float p = v + (row == col ? 1.000002f : 0.0f);
          u16 ph = f2bf(p);
          ((u16*)Cout)[g2] = ph;
          ((u16*)Cout)[g2 + 512] = f2bf(p - bf2f(ph));
          const float beta = 0.8264463f;
          u16 x1 = f2bf((row == col ? 2.0f * beta : 0.0f) - beta * beta * p);
          ((u16*)const_cast<void*>(aux))[gi] = x1;
          ((u16*)aux2)[g2] = x1;
          ((u16*)aux2)[g2 + 512] = x1;
        }
      }
    }
  }
}

// 256x256-tile bt-form bf16 MFMA gemm, 512 threads (8 waves, 2Mx4N), BK=64,
// 2 LDS K-tile buffers (128 KiB). ONE barrier per K-tile; during tile t we
// stage ONLY tile t+1 (all 4 halves) into buffer (t+1)&1 — never the buffer
// being read. [Race fix vs rounds 6-8: the old schedule staged tile t+2 into
// buffer t&1 inside the same inter-barrier window as that buffer's reads;
// a leading wave's global_load_lds could land before a lagging wave's
// ds_read -> replay-only corruption.] vmcnt(0) at tile end waits on loads
// issued a full tile earlier (near-free). LDS XOR-swizzle byte^=((row&7)<<4)
// applied both-sides. Tail tile stages nothing (uniform guard).
// EPI 0: f32 out = acc + aux[col] (bias) ; EPI 2: bf16 C = acc
template<int EPI>
__global__ __launch_bounds__(512, 2) void gemm256(const u16* __restrict__ A, const u16* __restrict__ B,
                                                  void* __restrict__ Cout, const float* __restrict__ aux,
                                                  int M, int N, int K){
  __shared__ __align__(16) char lds[131072];
  const int bz = blockIdx.z;
  const char* Ab = (const char*)(A + (size_t)bz * M * K);
  const char* Bb = (const char*)(B + (size_t)bz * N * K);
  const int NB = N >> 8;
  const int nwg = gridDim.x;
  const int bid = blockIdx.x;
  const int swzb = (bid & 7) * (nwg >> 3) + (bid >> 3);   // nwg % 8 == 0
  const int m0 = (swzb / NB) << 8;
  const int n0 = (swzb % NB) << 8;
  const int tid = threadIdx.x;
  const int w = tid >> 6, l = tid & 63;
  const int wm = w >> 2, wn = w & 3;
  const size_t Kb = (size_t)K << 1;
  const int NT = K >> 6;
  const int sRow = tid >> 3;
  const int sCol = ((tid & 7) << 4) ^ ((sRow & 7) << 4);
  const int sDst = tid << 4;
  const char* aS = Ab + (size_t)(m0 + sRow) * Kb + sCol;
  const char* bS = Bb + (size_t)(n0 + sRow) * Kb + sCol;
  const int lrow = (l & 15) << 7;
  const int kq0 = (((l >> 4) << 4)) ^ ((l & 7) << 4);
  const int aOff = (wm << 14) + lrow;
  const int bOff = 32768 + ((wn >> 1) << 14) + ((wn & 1) << 13) + lrow;

#define STAGE_H(isB, h, tt) { \
    const int _lo = (((tt) & 1) << 16) + ((isB) << 15) + ((h) << 14); \
    const char* _s = ((isB) ? bS : aS) + ((size_t)((h) << 7)) * Kb + ((size_t)(tt) << 7); \
    load16((const u16*)_s, (u16*)(lds + _lo + sDst)); \
    load16((const u16*)(_s + (Kb << 6)), (u16*)(lds + _lo + 8192 + sDst)); }

#define RD_A(bufb, UQ) \
  _Pragma("unroll") for (int i2 = 0; i2 < 4; ++i2){ \
    aF[i2][0] = *(const bf16x8*)(lds + (bufb) + aOff + ((UQ) << 13) + (i2 << 11) + kq0); \
    aF[i2][1] = *(const bf16x8*)(lds + (bufb) + aOff + ((UQ) << 13) + (i2 << 11) + (kq0 ^ 64)); }

#define RD_B(bufb, VQ) \
  _Pragma("unroll") for (int j2 = 0; j2 < 2; ++j2){ \
    bF[VQ][j2][0] = *(const bf16x8*)(lds + (bufb) + bOff + ((VQ) << 12) + (j2 << 11) + kq0); \
    bF[VQ][j2][1] = *(const bf16x8*)(lds + (bufb) + bOff + ((VQ) << 12) + (j2 << 11) + (kq0 ^ 64)); }

#define MFMA16(UQ, VQ) \
    _Pragma("unroll") for (int i2 = 0; i2 < 4; ++i2) \
      _Pragma("unroll") for (int j2 = 0; j2 < 2; ++j2){ \
        acc[(UQ)*4+i2][(VQ)*2+j2] = __builtin_amdgcn_mfma_f32_16x16x32_bf16(aF[i2][0], bF[VQ][j2][0], acc[(UQ)*4+i2][(VQ)*2+j2], 0, 0, 0); \
        acc[(UQ)*4+i2][(VQ)*2+j2] = __builtin_amdgcn_mfma_f32_16x16x32_bf16(aF[i2][1], bF[VQ][j2][1], acc[(UQ)*4+i2][(VQ)*2+j2], 0, 0, 0); }

#define BAR asm volatile("s_barrier" ::: "memory");
#define VM0 asm volatile("s_waitcnt vmcnt(0)" ::: "memory");

  bf16x8 aF[4][2], bF[2][2][2];
  f32x4 acc[8][4] = {};

  // prologue: stage tile 0 fully into buf 0
  STAGE_H(0,0,0) STAGE_H(1,0,0) STAGE_H(0,1,0) STAGE_H(1,1,0)
  VM0 BAR

  // one barrier per K-tile; stages target only the non-read buffer
#define KTILE(t, bufb) { \
    RD_A(bufb, 0) RD_B(bufb, 0) \
    if ((t) + 1 < NT) { STAGE_H(0,0,(t)+1) STAGE_H(1,0,(t)+1) } \
    MFMA16(0,0) \
    RD_B(bufb, 1) \
    if ((t) + 1 < NT) { STAGE_H(0,1,(t)+1) STAGE_H(1,1,(t)+1) } \
    MFMA16(0,1) \
    RD_A(bufb, 1) \
    MFMA16(1,1) \
    MFMA16(1,0) \
    __builtin_amdgcn_sched_barrier(0); \
    VM0 BAR }

#pragma unroll 1
  for (int tp = 0; tp < NT; tp += 2){
    KTILE(tp, 0)
    KTILE(tp+1, 65536)
  }
#undef KTILE
#undef STAGE_H
#undef RD_A
#undef RD_B
#undef MFMA16
#undef BAR
#undef VM0

#pragma unroll
  for (int mf = 0; mf < 8; ++mf){
#pragma unroll
    for (int nf = 0; nf < 4; ++nf){
      const int col = n0 + (wn << 6) + (nf << 4) + (l & 15);
#pragma unroll
      for (int q = 0; q < 4; ++q){
        const int row = m0 + (wm << 7) + (mf << 4) + ((l >> 4) << 2) + q;
        float v = acc[mf][nf][q];
        if (EPI == 0){
          ((float*)Cout)[(size_t)row * N + col] = v + aux[col];
        } else {
          ((u16*)Cout)[((size_t)bz * M + row) * N + col] = f2bf(v);
        }
      }
    }
  }
}

extern "C" void kernel_launch(void* const* d_in, const int* in_sizes, int n_in,
                              void* d_out, int out_size, void* d_ws, size_t ws_size,
                              hipStream_t stream){
  const float* W    = (const float*)d_in[0];
  const float* bias = (const float*)d_in[1];
  const float* x    = (const float*)d_in[2];
  const float* R    = (const float*)d_in[3];
  (void)in_sizes; (void)n_in; (void)out_size; (void)ws_size;

  char* ws = (char*)d_ws;
  const size_t MiB = (size_t)1 << 20;
  u16*   Sbf  = (u16*)(ws + 0 * MiB);    // 4 MiB ; reused as G
  u16*   Dbf  = (u16*)(ws + 4 * MiB);    // 4 MiB
  u16*   X1   = (u16*)(ws + 16 * MiB);   // 4 MiB ; reused as Rbf
  u16*   Ybf  = (u16*)(ws + 20 * MiB);   // 4 MiB ; reused as X3
  u16*   X2   = (u16*)(ws + 24 * MiB);   // 4 MiB
  u16*   Phl  = (u16*)(ws + 28 * MiB);   // 8 MiB  [Ph | Pl] width-1024
  u16*   X2d  = (u16*)(ws + 36 * MiB);   // 8 MiB  [X2 | X2] width-1024
  u16*   X1d  = (u16*)(ws + 44 * MiB);   // 8 MiB  [X1 | X1] width-1024
  u16*   Rbf  = X1;
  u16*   X3   = Ybf;
  u16*   G    = Sbf;
  u16*   Wt   = (u16*)(ws + 8 * MiB);    // 32 MiB [8,40) — NS temps there dead by then
  u16*   filt = (u16*)(ws + 64 * MiB);   // 32 MiB [64,96) — disjoint from xbf
  u16*   xbf  = (u16*)(ws + 0 * MiB);    // 64 MiB [0,64) — everything there dead by then

  const dim3 gNS(4, 4, 8);   // 128x128 tiles, proven gemm_bt

  // Phase 1: S (bf16) and D = (c+1)(cI - S)
  build_s<<<8192, 256, 0, stream>>>(R, Sbf, Dbf);
  // Phase 2: P = c^2 I + S S^T ; fused epilogue emits Phl=[Ph|Pl], X1, X1d
  gemm_bt<11><<<gNS, 256, 0, stream>>>(Sbf, Sbf, Phl, X1, X1d, 512, 512, 512);
  // Phase 3: Y = 2I - (Ph+Pl) X1   (one K=1024 gemm, full-precision P)
  gemm_bt<3><<<gNS, 256, 0, stream>>>(Phl, X1d, Ybf, nullptr, nullptr, 512, 512, 1024);
  // Phase 4: X2 = X1 Y (+ dup into X2d)
  gemm_bt<7><<<gNS, 256, 0, stream>>>(X1, Ybf, X2, X2d, nullptr, 512, 512, 512);
  // Phase 5: R = I - (Ph+Pl) X2   (one K=1024 gemm, bf16 out)
  gemm_bt<10><<<gNS, 256, 0, stream>>>(Phl, X2d, Rbf, nullptr, nullptr, 512, 512, 1024);
  // Phase 6: X3 = X2 + X2 R
  gemm_bt<6><<<gNS, 256, 0, stream>>>(X2, Rbf, X3, X2, nullptr, 512, 512, 512);
  // Phase 7: G = Q = D Pinv - I
  gemm_bt<9><<<gNS, 256, 0, stream>>>(Dbf, X3, G, nullptr, nullptr, 512, 512, 512);
  // Phase 8: filt = G @ Wb (bf16)
  transpose_w<<<dim3(128, 16, 8), 256, 0, stream>>>(W, Wt);
  gemm256<2><<<dim3(32, 1, 8), 512, 0, stream>>>(G, Wt, (void*)filt, nullptr, 512, 4096, 512);
  // Phase 9: x -> bf16
  conv_bf16<<<16384, 256, 0, stream>>>(x, xbf);
  // Phase 10: out = x @ filt^T + bias
  gemm256<0><<<dim3(512, 1, 1), 512, 0, stream>>>(xbf, filt, d_out, bias, 8192, 4096, 4096);
}